// Round 1
// baseline (180.232 us; speedup 1.0000x reference)
//
#include <hip/hip_runtime.h>
#include <math.h>

#define HH 1024
#define WW 1024
#define TS 16                 // output tile
#define HSZ 22                // halo'd tile (TS + 6)
#define REC 12                // floats per pixel record in LDS (3 x float4)
#define OFF(i) ((i)*8 - (i)*((i)-1)/2)   // packed upper-tri row offset

__global__ __launch_bounds__(256) void ls_solve_kernel(
    const float* __restrict__ inp,    // [3,H,W]
    const float* __restrict__ dep,    // [1,H,W]
    const float* __restrict__ alb,    // [3,H,W]
    const float* __restrict__ nrm,    // [3,H,W]
    float* __restrict__ out)          // [3,H,W]
{
    __shared__ float sm[HSZ * HSZ * REC];   // 23232 B

    const int tid = threadIdx.x;
    const int x0 = blockIdx.x * TS - 3;
    const int y0 = blockIdx.y * TS - 3;
    const int HW = HH * WW;

    // ---- stage halo'd feature records into LDS (zero-pad out-of-image) ----
    for (int i = tid; i < HSZ * HSZ; i += 256) {
        const int ly = i / HSZ;
        const int lx = i - ly * HSZ;
        const int gx = x0 + lx;
        const int gy = y0 + ly;
        float4 r0 = make_float4(0.f, 0.f, 0.f, 0.f);
        float4 r1 = r0, r2 = r0;
        if ((unsigned)gx < (unsigned)WW && (unsigned)gy < (unsigned)HH) {
            const int p = gy * WW + gx;
            r0.x = 1.0f;            // constant feature / validity
            r0.y = dep[p];
            r0.z = alb[p];
            r0.w = alb[p + HW];
            r1.x = alb[p + 2 * HW];
            r1.y = nrm[p];
            r1.z = nrm[p + HW];
            r1.w = nrm[p + 2 * HW];
            r2.x = inp[p];
            r2.y = inp[p + HW];
            r2.z = inp[p + 2 * HW];
            r2.w = 0.f;
        }
        float4* dst = (float4*)&sm[i * REC];
        dst[0] = r0; dst[1] = r1; dst[2] = r2;
    }
    __syncthreads();

    const int ox = tid & (TS - 1);
    const int oy = tid >> 4;

    // ---- accumulate normal equations over the 7x7 window ----
    float U[36];    // packed upper-tri AtA
    float Yv[24];   // AtY [8][3]
    #pragma unroll
    for (int i = 0; i < 36; i++) U[i] = 0.f;
    #pragma unroll
    for (int i = 0; i < 24; i++) Yv[i] = 0.f;

    #pragma unroll 1
    for (int dy = 0; dy < 7; dy++) {
        const float* row = &sm[((oy + dy) * HSZ + ox) * REC];
        #pragma unroll
        for (int dx = 0; dx < 7; dx++) {
            const float4* rp = (const float4*)(row + dx * REC);
            const float4 a = rp[0];
            const float4 b = rp[1];
            const float4 c = rp[2];
            const float fv[8] = {a.x, a.y, a.z, a.w, b.x, b.y, b.z, b.w};
            int k = 0;
            #pragma unroll
            for (int i = 0; i < 8; i++) {
                #pragma unroll
                for (int j = i; j < 8; j++) {
                    U[k] = fmaf(fv[i], fv[j], U[k]);
                    k++;
                }
            }
            #pragma unroll
            for (int i = 0; i < 8; i++) {
                Yv[i * 3 + 0] = fmaf(fv[i], c.x, Yv[i * 3 + 0]);
                Yv[i * 3 + 1] = fmaf(fv[i], c.y, Yv[i * 3 + 1]);
                Yv[i * 3 + 2] = fmaf(fv[i], c.z, Yv[i * 3 + 2]);
            }
        }
    }

    // ---- fp64 Cholesky: A = U^T U (upper-tri, packed) ----
    double A[36];
    #pragma unroll
    for (int i = 0; i < 36; i++) A[i] = (double)U[i];
    #pragma unroll
    for (int i = 0; i < 8; i++) A[OFF(i)] += 1.0e-4;   // Tikhonov eps (exact, like np ref)

    double invd[8];
    #pragma unroll
    for (int i = 0; i < 8; i++) {
        double s = A[OFF(i)];
        #pragma unroll
        for (int k2 = 0; k2 < i; k2++) {
            const double u = A[OFF(k2) + i - k2];
            s -= u * u;
        }
        const double d = sqrt(s);
        const double id = 1.0 / d;
        invd[i] = id;
        #pragma unroll
        for (int j = i + 1; j < 8; j++) {
            double s2 = A[OFF(i) + j - i];
            #pragma unroll
            for (int k2 = 0; k2 < i; k2++)
                s2 -= A[OFF(k2) + i - k2] * A[OFF(k2) + j - k2];
            A[OFF(i) + j - i] = s2 * id;
        }
    }

    // center pixel features
    const float4* cp = (const float4*)&sm[((oy + 3) * HSZ + (ox + 3)) * REC];
    const float4 ca = cp[0], cb = cp[1];
    const float cf[8] = {ca.x, ca.y, ca.z, ca.w, cb.x, cb.y, cb.z, cb.w};

    const int gx = x0 + 3 + ox;   // always in-range: grid tiles image exactly
    const int gy = y0 + 3 + oy;
    const int p = gy * WW + gx;

    // ---- triangular solves per RHS column, then evaluate at center ----
    #pragma unroll
    for (int c = 0; c < 3; c++) {
        double z[8];
        #pragma unroll
        for (int i = 0; i < 8; i++) {
            double s = (double)Yv[i * 3 + c];
            #pragma unroll
            for (int k2 = 0; k2 < i; k2++)
                s -= A[OFF(k2) + i - k2] * z[k2];
            z[i] = s * invd[i];
        }
        double xs[8];
        #pragma unroll
        for (int i = 7; i >= 0; i--) {
            double s = z[i];
            #pragma unroll
            for (int j = i + 1; j < 8; j++)
                s -= A[OFF(i) + j - i] * xs[j];
            xs[i] = s * invd[i];
        }
        double r = 0.0;
        #pragma unroll
        for (int i = 0; i < 8; i++) r += xs[i] * (double)cf[i];
        out[c * HW + p] = (float)r;
    }
}

extern "C" void kernel_launch(void* const* d_in, const int* in_sizes, int n_in,
                              void* d_out, int out_size, void* d_ws, size_t ws_size,
                              hipStream_t stream) {
    const float* inp = (const float*)d_in[0];
    const float* dep = (const float*)d_in[1];
    const float* alb = (const float*)d_in[2];
    const float* nrm = (const float*)d_in[3];
    float* out = (float*)d_out;
    dim3 grid(WW / TS, HH / TS);
    ls_solve_kernel<<<grid, dim3(256), 0, stream>>>(inp, dep, alb, nrm, out);
}

// Round 3
// 170.312 us; speedup vs baseline: 1.0582x; 1.0582x over previous
//
#include <hip/hip_runtime.h>
#include <math.h>

#define HH 1024
#define WW 1024
#define OUTW 58            // output columns per wave (64 lanes - 6 halo)
#define RPB 8              // output rows per block (vertical slide length)
#define OFF(i) ((i)*8 - (i)*((i)-1)/2)   // packed upper-tri row offset

// DPP move with old=0 (invalid source lanes contribute 0)
template<int CTRL>
__device__ __forceinline__ float dpp0(float x) {
    return __int_as_float(
        __builtin_amdgcn_update_dpp(0, __float_as_int(x), CTRL, 0xf, 0xf, false));
}
// whole-wave shift right by 1 lane (crosses 16-lane row boundaries)
__device__ __forceinline__ float wshr1(float x) { return dpp0<0x138>(x); }

__global__ __launch_bounds__(64, 2) void ls_sep_kernel(
    const float* __restrict__ inp,    // [3,H,W]
    const float* __restrict__ dep,    // [1,H,W]
    const float* __restrict__ alb,    // [3,H,W]
    const float* __restrict__ nrm,    // [3,H,W]
    float* __restrict__ out)          // [3,H,W]
{
    const int L  = threadIdx.x;               // lane 0..63
    const int HW = HH * WW;
    // lane L sums column x; its horizontal window (x-6..x) is centered at x-3
    const int x  = OUTW * blockIdx.x - 3 + L;
    const int y0 = RPB * blockIdx.y;
    const int px = x - 3;                     // output pixel column for this lane

    const int xc    = min(max(x, 0), WW - 1);
    const float xok = (x >= 0 && x < WW) ? 1.f : 0.f;

    float C[60];                              // running column sums (7 rows in y)
    #pragma unroll
    for (int k = 0; k < 60; k++) C[k] = 0.f;

    auto acc_row = [&](int yy, float sgn) {
        const int yc = min(max(yy, 0), HH - 1);
        const float ok = (yy >= 0 && yy < HH) ? xok : 0.f;
        const int p = yc * WW + xc;
        float fv[8], yv[3];
        fv[0] = 1.f;
        fv[1] = dep[p];
        fv[2] = alb[p];
        fv[3] = alb[p + HW];
        fv[4] = alb[p + 2 * HW];
        fv[5] = nrm[p];
        fv[6] = nrm[p + HW];
        fv[7] = nrm[p + 2 * HW];
        yv[0] = inp[p];
        yv[1] = inp[p + HW];
        yv[2] = inp[p + 2 * HW];
        const float s = sgn * ok;
        float fs[8];
        #pragma unroll
        for (int i = 0; i < 8; i++) fs[i] = fv[i] * s;
        int k = 0;
        #pragma unroll
        for (int i = 0; i < 8; i++)
            #pragma unroll
            for (int j = i; j < 8; j++) { C[k] = fmaf(fs[i], fv[j], C[k]); k++; }
        #pragma unroll
        for (int i = 0; i < 8; i++)
            #pragma unroll
            for (int c = 0; c < 3; c++)
                C[36 + i * 3 + c] = fmaf(fs[i], yv[c], C[36 + i * 3 + c]);
    };

    // preload rows y0-4 .. y0+2  (window for first output row y0 needs y0-3..y0+3;
    // loop body does add(y+3), sub(y-4) — so preload must include y0-4)
    #pragma unroll 1
    for (int yy = y0 - 4; yy < y0 + 3; yy++) acc_row(yy, 1.f);

    const int idxm4 = ((L - 4) & 63) << 2;    // bpermute byte index for lane L-4
    const int pxc = min(max(px, 0), WW - 1);
    const bool do_store = (L >= 6) && (px < WW);

    #pragma unroll 1
    for (int y = y0; y < y0 + RPB; y++) {
        acc_row(y + 3, 1.f);
        acc_row(y - 4, -1.f);

        // exact horizontal 7-tap: S(L) = sum of C over lanes L-6..L
        float S[60];
        #pragma unroll
        for (int k = 0; k < 60; k++) {
            const float xv = C[k];
            const float w1 = wshr1(xv);       // C(L-1)
            const float t1 = xv + w1;         // L-1..L
            const float w2 = wshr1(w1);       // C(L-2)
            const float t3 = t1 + w2;         // L-2..L
            const float w3 = wshr1(w2);       // C(L-3)
            const float t2 = t3 + w3;         // L-3..L
            const float pm = __int_as_float(
                __builtin_amdgcn_ds_bpermute(idxm4, __float_as_int(t3))); // L-6..L-4
            S[k] = t2 + pm;
        }

        // center-pixel features (column px, row y)
        const int pc = y * WW + pxc;
        float cf[8];
        cf[0] = 1.f;
        cf[1] = dep[pc];
        cf[2] = alb[pc];
        cf[3] = alb[pc + HW];
        cf[4] = alb[pc + 2 * HW];
        cf[5] = nrm[pc];
        cf[6] = nrm[pc + HW];
        cf[7] = nrm[pc + 2 * HW];

        // fp64 Cholesky of AtA (+eps I), packed upper-tri
        double A[36];
        #pragma unroll
        for (int k = 0; k < 36; k++) A[k] = (double)S[k];
        #pragma unroll
        for (int i = 0; i < 8; i++) A[OFF(i)] += 1.0e-4;

        double invd[8];
        #pragma unroll
        for (int i = 0; i < 8; i++) {
            double s = A[OFF(i)];
            #pragma unroll
            for (int k2 = 0; k2 < i; k2++) {
                const double u = A[OFF(k2) + i - k2];
                s -= u * u;
            }
            const double id = 1.0 / sqrt(s);
            invd[i] = id;
            #pragma unroll
            for (int j = i + 1; j < 8; j++) {
                double s2 = A[OFF(i) + j - i];
                #pragma unroll
                for (int k2 = 0; k2 < i; k2++)
                    s2 -= A[OFF(k2) + i - k2] * A[OFF(k2) + j - k2];
                A[OFF(i) + j - i] = s2 * id;
            }
        }

        // solve A w = f_center (single RHS), then out_c = w . AtY_c
        double z[8];
        #pragma unroll
        for (int i = 0; i < 8; i++) {
            double s = (double)cf[i];
            #pragma unroll
            for (int k2 = 0; k2 < i; k2++)
                s -= A[OFF(k2) + i - k2] * z[k2];
            z[i] = s * invd[i];
        }
        double w[8];
        #pragma unroll
        for (int i = 7; i >= 0; i--) {
            double s = z[i];
            #pragma unroll
            for (int j = i + 1; j < 8; j++)
                s -= A[OFF(i) + j - i] * w[j];
            w[i] = s * invd[i];
        }

        if (do_store) {
            const int p = y * WW + px;
            #pragma unroll
            for (int c = 0; c < 3; c++) {
                double r = 0.0;
                #pragma unroll
                for (int i = 0; i < 8; i++)
                    r += w[i] * (double)S[36 + i * 3 + c];
                out[c * HW + p] = (float)r;
            }
        }
    }
}

extern "C" void kernel_launch(void* const* d_in, const int* in_sizes, int n_in,
                              void* d_out, int out_size, void* d_ws, size_t ws_size,
                              hipStream_t stream) {
    const float* inp = (const float*)d_in[0];
    const float* dep = (const float*)d_in[1];
    const float* alb = (const float*)d_in[2];
    const float* nrm = (const float*)d_in[3];
    float* out = (float*)d_out;
    dim3 grid((WW + OUTW - 1) / OUTW, HH / RPB);   // 18 x 128
    ls_sep_kernel<<<grid, dim3(64), 0, stream>>>(inp, dep, alb, nrm, out);
}